// Round 13
// baseline (114.353 us; speedup 1.0000x reference)
//
#include <hip/hip_runtime.h>

#define VOCAB 10000
#define EMB   16
#define HID   32
#define BATCH 4096
#define TLEN  512

typedef _Float16 f16x4 __attribute__((ext_vector_type(4)));
typedef _Float16 f16x2 __attribute__((ext_vector_type(2)));
typedef float    f32x4 __attribute__((ext_vector_type(4)));

// ---------------------------------------------------------------------------
// Kernel 1: P[v][j] = b[j] + sum_e emb[v][e] * Wx[e][j]   (fp32 table in ws)
// ---------------------------------------------------------------------------
__global__ __launch_bounds__(256) void rnn_proj(
    const float* __restrict__ emb, const float* __restrict__ Wx,
    const float* __restrict__ bias, float* __restrict__ P)
{
    int tid = blockIdx.x * 256 + threadIdx.x;
    if (tid >= VOCAB * HID) return;
    int v = tid >> 5;
    int j = tid & 31;
    float acc = bias[j];
    const float* ev = emb + v * EMB;
#pragma unroll
    for (int e = 0; e < EMB; ++e) {
        acc = fmaf(ev[e], Wx[e * HID + j], acc);
    }
    P[tid] = acc;
}

// ---------------------------------------------------------------------------
// Kernel 2: self-feeding MFMA scan. One wave = 16 batches; the whole
// recurrence lives in registers.
//   z^T[j][b] = P^T[j][b] + sum_i Wh^T[j][i] * h^T[i][b]
// as v_mfma_f32_16x16x16_f16 with A = Wh^T (constant frags), B = h^T.
// Layout identity: D frag (row=4*(l>>4)+r, col=l&15) == B frag
// (k=4*(l>>4)+r, col=l&15), so D -> tanh -> cvt_pkrtz -> next B is fully
// lane-local. No LDS, no shuffles, no cross-lane h traffic.
// C-operand carries the P tile: lane loads float4 P[tok(b=l&15)][4*(l>>4)..]
// (tile0) and +16 (tile1); a wave-step covers each P row exactly once.
// Tokens as int4 quads; P prefetched one quad (~600cy) ahead.
// ---------------------------------------------------------------------------
__global__ __launch_bounds__(64)
__attribute__((amdgpu_waves_per_eu(1, 1)))
void rnn_scan(
    const int*   __restrict__ x,   const float* __restrict__ P,
    const float* __restrict__ Wh,  const float* __restrict__ Wd,
    const float* __restrict__ bd,  float* __restrict__ out)
{
    const int l  = threadIdx.x & 63;
    const int bq = l & 15;                      // batch within tile / A-row j
    const int kg = l >> 4;                      // k-group: k/j-quad = 4*kg..+3
    const int bt = blockIdx.x * 16;             // batch tile base

    // A = Wh^T fragments: lane holds A[row][k] = Wh[k][row], k = 4*kg+r
    f16x4 A00, A01, A10, A11;                   // [tile j-half][k-half]
#pragma unroll
    for (int r = 0; r < 4; ++r) {
        A00[r] = (_Float16)Wh[(4 * kg + r)      * HID + bq];        // j 0-15,  i 0-15
        A01[r] = (_Float16)Wh[(16 + 4 * kg + r) * HID + bq];        // j 0-15,  i 16-31
        A10[r] = (_Float16)Wh[(4 * kg + r)      * HID + 16 + bq];   // j 16-31, i 0-15
        A11[r] = (_Float16)Wh[(16 + 4 * kg + r) * HID + 16 + bq];   // j 16-31, i 16-31
    }

    const int*   xb = x + (bt + bq) * TLEN;     // lanes 16+ dup lanes 0-15 (same line)
    const float* Pg = P + 4 * kg;               // lane's j-quad base in a P row

    // token quads
    int4 tq_cur = *(const int4*)(xb);           // steps 0..3
    int4 tq_nxt = *(const int4*)(xb + 4);       // steps 4..7

    // P for quad 0 (prologue latency accepted once)
    f32x4 pc0a = *(const f32x4*)(Pg + tq_cur.x * HID);
    f32x4 pc0b = *(const f32x4*)(Pg + tq_cur.x * HID + 16);
    f32x4 pc1a = *(const f32x4*)(Pg + tq_cur.y * HID);
    f32x4 pc1b = *(const f32x4*)(Pg + tq_cur.y * HID + 16);
    f32x4 pc2a = *(const f32x4*)(Pg + tq_cur.z * HID);
    f32x4 pc2b = *(const f32x4*)(Pg + tq_cur.z * HID + 16);
    f32x4 pc3a = *(const f32x4*)(Pg + tq_cur.w * HID);
    f32x4 pc3b = *(const f32x4*)(Pg + tq_cur.w * HID + 16);

    f16x4 B0 = {};                              // h^T, i 0-15  (starts at 0)
    f16x4 B1 = {};                              // h^T, i 16-31

    const float TWO_LOG2E = 2.8853900817779268f;   // 2*log2(e)

#define TANH(Z) ({ float _e2 = __builtin_amdgcn_exp2f((Z) * TWO_LOG2E);       \
                   fmaf(-2.0f, __builtin_amdgcn_rcpf(_e2 + 1.0f), 1.0f); })

#define STEP(PA, PB)                                                          \
    {                                                                         \
        f32x4 z0 = __builtin_amdgcn_mfma_f32_16x16x16f16(A00, B0, (PA), 0, 0, 0); \
        f32x4 z1 = __builtin_amdgcn_mfma_f32_16x16x16f16(A10, B0, (PB), 0, 0, 0); \
        z0 = __builtin_amdgcn_mfma_f32_16x16x16f16(A01, B1, z0, 0, 0, 0);     \
        z1 = __builtin_amdgcn_mfma_f32_16x16x16f16(A11, B1, z1, 0, 0, 0);     \
        float t00 = TANH(z0[0]), t01 = TANH(z0[1]);                           \
        float t02 = TANH(z0[2]), t03 = TANH(z0[3]);                           \
        float t10 = TANH(z1[0]), t11 = TANH(z1[1]);                           \
        float t12 = TANH(z1[2]), t13 = TANH(z1[3]);                           \
        f16x2 q0 = __builtin_bit_cast(f16x2, __builtin_amdgcn_cvt_pkrtz(t00, t01)); \
        f16x2 q1 = __builtin_bit_cast(f16x2, __builtin_amdgcn_cvt_pkrtz(t02, t03)); \
        f16x2 q2 = __builtin_bit_cast(f16x2, __builtin_amdgcn_cvt_pkrtz(t10, t11)); \
        f16x2 q3 = __builtin_bit_cast(f16x2, __builtin_amdgcn_cvt_pkrtz(t12, t13)); \
        B0 = __builtin_shufflevector(q0, q1, 0, 1, 2, 3);                     \
        B1 = __builtin_shufflevector(q2, q3, 0, 1, 2, 3);                     \
    }

    const int NQ = TLEN / 4;                    // 128 quads, exact

    for (int k = 0; k < NQ; ++k) {
        // prefetch P for quad k+1 (tokens already resident in tq_nxt)
        f32x4 pn0a = *(const f32x4*)(Pg + tq_nxt.x * HID);
        f32x4 pn0b = *(const f32x4*)(Pg + tq_nxt.x * HID + 16);
        f32x4 pn1a = *(const f32x4*)(Pg + tq_nxt.y * HID);
        f32x4 pn1b = *(const f32x4*)(Pg + tq_nxt.y * HID + 16);
        f32x4 pn2a = *(const f32x4*)(Pg + tq_nxt.z * HID);
        f32x4 pn2b = *(const f32x4*)(Pg + tq_nxt.z * HID + 16);
        f32x4 pn3a = *(const f32x4*)(Pg + tq_nxt.w * HID);
        f32x4 pn3b = *(const f32x4*)(Pg + tq_nxt.w * HID + 16);
        // prefetch token quad k+2 (clamped; tail values unused)
        int  q2i = (k + 2 < NQ) ? (k + 2) : (NQ - 1);
        int4 tq2 = *(const int4*)(xb + 4 * q2i);

        STEP(pc0a, pc0b)
        STEP(pc1a, pc1b)
        STEP(pc2a, pc2b)
        STEP(pc3a, pc3b)

        pc0a = pn0a; pc0b = pn0b; pc1a = pn1a; pc1b = pn1b;
        pc2a = pn2a; pc2b = pn2b; pc3a = pn3a; pc3b = pn3b;
        tq_nxt = tq2;
    }
#undef STEP
#undef TANH

    // h^T[j][b]: B0 -> j = 4*kg+r, B1 -> j = 16+4*kg+r, b = bt + (l&15)
    // out[b] = sigmoid(sum_j h[b][j] * Wd[j] + bd)
    float s = 0.0f;
#pragma unroll
    for (int r = 0; r < 4; ++r) {
        s = fmaf((float)B0[r], Wd[4 * kg + r],      s);
        s = fmaf((float)B1[r], Wd[16 + 4 * kg + r], s);
    }
    s += __shfl_xor(s, 16, 64);                 // reduce over the 4 kg-groups
    s += __shfl_xor(s, 32, 64);
    if (l < 16) {
        float logit = s + bd[0];
        out[bt + l] = 1.0f / (1.0f + __expf(-logit));
    }
}

// ---------------------------------------------------------------------------
extern "C" void kernel_launch(void* const* d_in, const int* in_sizes, int n_in,
                              void* d_out, int out_size, void* d_ws, size_t ws_size,
                              hipStream_t stream)
{
    const int*   x   = (const int*)  d_in[0];
    const float* emb = (const float*)d_in[1];
    const float* Wx  = (const float*)d_in[2];
    const float* Wh  = (const float*)d_in[3];
    const float* bia = (const float*)d_in[4];
    const float* Wd  = (const float*)d_in[5];
    const float* bd  = (const float*)d_in[6];
    float* out = (float*)d_out;

    float* P = (float*)d_ws;                    // VOCAB*HID*4 = 1.28 MB

    rnn_proj<<<(VOCAB * HID + 255) / 256, 256, 0, stream>>>(emb, Wx, bia, P);
    rnn_scan<<<BATCH / 16, 64, 0, stream>>>(x, P, Wh, Wd, bd, out);
}